// Round 9
// baseline (117.601 us; speedup 1.0000x reference)
//
#include <hip/hip_runtime.h>
#include <math.h>

#define NUM_TASKS 16
#define B_ROWS    8192
#define TROWS     48               // rows per fused tile (3 x 16)
#define NB_FUSED  186              // max tiles: floor(8192/48) + 16
#define P_ROWS    8960             // padded sorted-row space (tasks 48-aligned)

typedef __attribute__((ext_vector_type(4))) float f32x4;
typedef __attribute__((ext_vector_type(8))) short bf16x8;
typedef __attribute__((ext_vector_type(4))) short bf16x4;
typedef unsigned short ushort_t;

__device__ __forceinline__ short f2bf(float f) {
    union { float f; unsigned u; } c; c.f = f;
    unsigned u = c.u;
    unsigned r = (u + 0x7FFFu + ((u >> 16) & 1u)) >> 16;
    return (short)r;
}

__device__ __forceinline__ float fast_tanh(float x) {
    float e = __expf(2.0f * x);
    return 1.0f - 2.0f / (e + 1.0f);
}

// ---------------------------------------------------------------------------
// W layout (per task, per-wave granules; WN = NFPW*16 cols per wave):
//   elem(n,k;K,WN) = ((n/WN)*(K/32) + (k>>5)) * (WN*32)
//                  + ((n%WN)>>4)*512 + ((k>>3)&3)*128 + (n&15)*8 + (k&7)
// One wave's NFPW fragments for one k32-step = NFPW KB CONTIGUOUS.
// Lane l reads 16B of fragment nf at granule + nf*1024 + (l>>4)*256 + (l&15)*16.
// H (LDS) layout unchanged from R8: 16-row groups, XOR slot swizzle
//   ((x&15) ^ (kg&7)) — conflict-free read & write.
// ---------------------------------------------------------------------------

// ---------------------------------------------------------------------------
// Bucket kernel: stable counting sort of rows by task, tasks padded to 48.
// ---------------------------------------------------------------------------
__global__ __launch_bounds__(256) void bucket_kernel(
    const int* __restrict__ task_ids,
    int* __restrict__ sidx,
    int* __restrict__ tile_base,
    int* __restrict__ tile_task,
    int* __restrict__ tile_end,
    int* __restrict__ ntiles)
{
    __shared__ int cnt[256][NUM_TASKS];
    __shared__ int pstart[NUM_TASKS];
    __shared__ int tot[NUM_TASKS];

    const int tid = threadIdx.x;
    #pragma unroll
    for (int t = 0; t < NUM_TASKS; ++t) cnt[tid][t] = 0;
    const int base = tid * (B_ROWS / 256);

    for (int i = 0; i < B_ROWS / 256; ++i) {
        int t = task_ids[base + i];
        cnt[tid][t]++;
    }
    __syncthreads();

    if (tid < NUM_TASKS) {
        int s = 0;
        for (int c = 0; c < 256; ++c) { int v = cnt[c][tid]; cnt[c][tid] = s; s += v; }
        tot[tid] = s;
    }
    __syncthreads();

    if (tid == 0) {
        int p = 0, nt = 0;
        for (int t = 0; t < NUM_TASKS; ++t) {
            pstart[t] = p;
            for (int r = 0; r < tot[t]; r += TROWS) {
                tile_base[nt] = p + r;
                tile_task[nt] = t;
                tile_end[nt]  = p + tot[t];
                nt++;
            }
            p += ((tot[t] + TROWS - 1) / TROWS) * TROWS;
        }
        *ntiles = nt;
    }
    __syncthreads();

    for (int i = 0; i < P_ROWS / 256; ++i) sidx[tid + i * 256] = 0;
    __syncthreads();

    for (int i = 0; i < B_ROWS / 256; ++i) {
        int row = base + i;
        int t = task_ids[row];
        int pos = pstart[t] + cnt[tid][t];
        cnt[tid][t] = cnt[tid][t] + 1;
        sidx[pos] = row;
    }
}

// ---------------------------------------------------------------------------
// Weight convert + transpose + pack into per-wave granule layout.
// ---------------------------------------------------------------------------
template<int K, int N, int WN>
__global__ __launch_bounds__(256) void wconv(
    const float* __restrict__ W, ushort_t* __restrict__ Wt)
{
    const int t  = blockIdx.z;
    const int kb = blockIdx.y * 64;
    const int nb = blockIdx.x * 64;
    const float* src = W + (size_t)t * K * N;
    ushort_t* dst = Wt + (size_t)t * N * K;

    __shared__ ushort_t tile[64][68];

    const int tid = threadIdx.x;
    {
        int kl  = tid >> 4;
        int nl4 = (tid & 15) * 4;
        #pragma unroll
        for (int r = 0; r < 4; ++r) {
            int k = kl + r * 16;
            f32x4 v = *(const f32x4*)(src + (size_t)(kb + k) * N + nb + nl4);
            tile[nl4 + 0][k] = (ushort_t)f2bf(v[0]);
            tile[nl4 + 1][k] = (ushort_t)f2bf(v[1]);
            tile[nl4 + 2][k] = (ushort_t)f2bf(v[2]);
            tile[nl4 + 3][k] = (ushort_t)f2bf(v[3]);
        }
    }
    __syncthreads();
    {
        int nl = tid >> 2;            // 0..63 local n
        int c  = (tid & 3) * 16;      // local k chunk of 16
        int n  = nb + nl;
        int k0 = kb + c;
        bf16x4 v0 = *(const bf16x4*)&tile[nl][c + 0];
        bf16x4 v1 = *(const bf16x4*)&tile[nl][c + 4];
        bf16x4 v2 = *(const bf16x4*)&tile[nl][c + 8];
        bf16x4 v3 = *(const bf16x4*)&tile[nl][c + 12];
        ushort_t* dg = dst
            + ((size_t)(n / WN) * (K / 32) + (k0 >> 5)) * (WN * 32)
            + (size_t)((n % WN) >> 4) * 512
            + ((k0 >> 3) & 3) * 128 + (n & 15) * 8;
        *(bf16x4*)(dg + 0)   = v0;
        *(bf16x4*)(dg + 4)   = v1;
        *(bf16x4*)(dg + 128) = v2;
        *(bf16x4*)(dg + 132) = v3;
    }
}

// ---------------------------------------------------------------------------
// One fused-MLP layer with explicit 4-slot W register pipeline.
// Per step: ds_read h[3] -> MFMA 3xNFPW on wreg[s&3] -> reissue slot for s+4.
// Steady state: 3 batches (3*NFPW loads, ~24KB/wave) in flight. No barriers
// inside the K-loop.
// ---------------------------------------------------------------------------
template<int NFPW>
__device__ __forceinline__ void load_wbatch(bf16x8* dst, const char* pw) {
    constexpr int LO = NFPW < 4 ? NFPW : 4;
    #pragma unroll
    for (int nf = 0; nf < LO; ++nf)
        dst[nf] = *(const bf16x8*)(pw + nf * 1024);
    if constexpr (NFPW > 4) {
        const char* pw2 = pw + 4096;
        #pragma unroll
        for (int nf = 4; nf < NFPW; ++nf)
            dst[nf] = *(const bf16x8*)(pw2 + (nf - 4) * 1024);
    }
}

template<int K, int NNOUT, int NFPW, int INPLACE, int FINAL>
__device__ __forceinline__ void run_layer(
    const char* __restrict__ Hin,
    char* __restrict__ Hout,
    const ushort_t* __restrict__ Wt,      // task's packed weights
    const float* __restrict__ bias,       // task's bias
    float* __restrict__ outp,
    const int* __restrict__ sidx,
    int rowbase, int rowend, int lane, int wid)
{
    constexpr int NS   = K / 32;           // k32 steps (16 or 32; %4==0)
    constexpr int WN   = NFPW * 16;
    constexpr int GRAN = WN * 64;          // bytes per (wave, k32) granule
    const int nbase = wid * WN;

    const char* pw = (const char*)Wt + (size_t)wid * (K / 32) * GRAN
                   + (lane >> 4) * 256 + (lane & 15) * 16;

    f32x4 acc[3][NFPW];
    #pragma unroll
    for (int mf = 0; mf < 3; ++mf)
        #pragma unroll
        for (int nf = 0; nf < NFPW; ++nf)
            acc[mf][nf] = (f32x4){0.f, 0.f, 0.f, 0.f};

    bf16x8 wreg[4][NFPW];
    #pragma unroll
    for (int b = 0; b < 4; ++b) {
        load_wbatch<NFPW>(wreg[b], pw);
        pw += GRAN;
    }

    #pragma unroll
    for (int s = 0; s < NS; ++s) {
        bf16x8 h[3];
        const int kg = s * 4 + (lane >> 4);
        #pragma unroll
        for (int mf = 0; mf < 3; ++mf)
            h[mf] = *(const bf16x8*)(Hin
                        + ((size_t)(mf * (K / 8) + kg) * 256)
                        + (((lane & 15) ^ (kg & 7)) * 16));
        __builtin_amdgcn_s_setprio(1);
        #pragma unroll
        for (int mf = 0; mf < 3; ++mf)
            #pragma unroll
            for (int nf = 0; nf < NFPW; ++nf)
                acc[mf][nf] = __builtin_amdgcn_mfma_f32_16x16x32_bf16(
                    wreg[s & 3][nf], h[mf], acc[mf][nf], 0, 0, 0);
        __builtin_amdgcn_s_setprio(0);
        if (s + 4 < NS) {                  // compile-time (unrolled)
            load_wbatch<NFPW>(wreg[s & 3], pw);
            pw += GRAN;
        }
    }

    const int q   = lane >> 4;
    const int m15 = lane & 15;

    if (!FINAL) {
        if (INPLACE) __syncthreads();      // all waves done reading H_in
        #pragma unroll
        for (int mf = 0; mf < 3; ++mf) {
            #pragma unroll
            for (int nf = 0; nf < NFPW; ++nf) {
                const int n_lo = nbase + nf * 16 + q * 4;
                const f32x4 bb = *(const f32x4*)(bias + n_lo);
                bf16x4 pk;
                #pragma unroll
                for (int r = 0; r < 4; ++r)
                    pk[r] = f2bf(fast_tanh(acc[mf][nf][r] + bb[r]));
                const int kg2 = n_lo >> 3;
                size_t off = ((size_t)(mf * (NNOUT / 8) + kg2) * 256)
                           + ((m15 ^ (kg2 & 7)) * 16) + (n_lo & 7) * 2;
                *(bf16x4*)(Hout + off) = pk;
            }
        }
        __syncthreads();                   // H_out complete
    } else {
        #pragma unroll
        for (int mf = 0; mf < 3; ++mf) {
            const int grow = rowbase + mf * 16 + m15;
            if (grow < rowend) {
                const int orow = sidx[grow];
                #pragma unroll
                for (int nf = 0; nf < NFPW; ++nf) {
                    const int n_lo = nbase + nf * 16 + q * 4;
                    const f32x4 bb = *(const f32x4*)(bias + n_lo);
                    f32x4 v;
                    #pragma unroll
                    for (int r = 0; r < 4; ++r)
                        v[r] = acc[mf][nf][r] + bb[r];
                    *(f32x4*)(outp + (size_t)orow * 256 + n_lo) = v;
                }
            }
        }
    }
}

// ---------------------------------------------------------------------------
// Fused 3-layer MLP: one 512-thread block per 48-row tile.
// LDS 144 KB: H region 96 KB + x region 48 KB. launch_bounds(512,2): 256-VGPR
// cap (wreg 128 + acc 96 AGPR + h 12 + addr ~ 246).
// ---------------------------------------------------------------------------
__global__ __launch_bounds__(512, 2) void fused_mlp(
    const float* __restrict__ x,
    const ushort_t* __restrict__ Wt0,
    const ushort_t* __restrict__ Wt1,
    const ushort_t* __restrict__ Wt2,
    const float* __restrict__ b0,
    const float* __restrict__ b1,
    const float* __restrict__ b2,
    float* __restrict__ out,
    const int* __restrict__ sidx,
    const int* __restrict__ tile_base,
    const int* __restrict__ tile_task,
    const int* __restrict__ tile_end,
    const int* __restrict__ ntiles)
{
    __shared__ __align__(16) char lds[147456];
    char* Hreg = lds;            // 96 KB
    char* Xreg = lds + 98304;    // 48 KB

    // bijective XCD mapping (m204): contiguous ~23-tile (~2-task) chunk/XCD
    const int orig = blockIdx.x;
    constexpr int q8 = NB_FUSED / 8, r8 = NB_FUSED % 8;
    const int xcd = orig & 7, idx = orig >> 3;
    const int tile = (xcd < r8 ? xcd * (q8 + 1) : r8 * (q8 + 1) + (xcd - r8) * q8) + idx;

    if (tile >= *ntiles) return;
    const int rowbase = tile_base[tile];
    const int task    = tile_task[tile];
    const int rowend  = tile_end[tile];

    const int tid  = threadIdx.x;
    const int lane = tid & 63;
    const int wid  = tid >> 6;

    // ---- gather + convert x tile (48 rows x 512 fp32) into packed LDS ----
    #pragma unroll
    for (int i = 0; i < 6; ++i) {
        const int row = wid + i * 8;
        const int src = sidx[rowbase + row];
        const float* sp = x + (size_t)src * 512 + lane * 8;
        f32x4 v0 = *(const f32x4*)sp;
        f32x4 v1 = *(const f32x4*)(sp + 4);
        bf16x8 pk;
        pk[0] = f2bf(v0[0]); pk[1] = f2bf(v0[1]);
        pk[2] = f2bf(v0[2]); pk[3] = f2bf(v0[3]);
        pk[4] = f2bf(v1[0]); pk[5] = f2bf(v1[1]);
        pk[6] = f2bf(v1[2]); pk[7] = f2bf(v1[3]);
        size_t off = ((size_t)((row >> 4) * 64 + lane) * 256)
                   + (((row & 15) ^ (lane & 7)) * 16);
        *(bf16x8*)(Xreg + off) = pk;
    }
    __syncthreads();

    run_layer< 512, 1024, 8, 0, 0>(Xreg, Hreg,
                                   Wt0 + (size_t)task * 512 * 1024,
                                   b0 + task * 1024, nullptr, sidx,
                                   rowbase, rowend, lane, wid);
    run_layer<1024, 1024, 8, 1, 0>(Hreg, Hreg,
                                   Wt1 + (size_t)task * 1024 * 1024,
                                   b1 + task * 1024, nullptr, sidx,
                                   rowbase, rowend, lane, wid);
    run_layer<1024,  256, 2, 0, 1>(Hreg, nullptr,
                                   Wt2 + (size_t)task * 1024 * 256,
                                   b2 + task * 256, out, sidx,
                                   rowbase, rowend, lane, wid);
}

// ---------------------------------------------------------------------------
extern "C" void kernel_launch(void* const* d_in, const int* in_sizes, int n_in,
                              void* d_out, int out_size, void* d_ws, size_t ws_size,
                              hipStream_t stream)
{
    const float* x        = (const float*)d_in[0];
    const int*   task_ids = (const int*)  d_in[1];
    const float* k0       = (const float*)d_in[2];
    const float* b0       = (const float*)d_in[3];
    const float* k1       = (const float*)d_in[4];
    const float* b1       = (const float*)d_in[5];
    const float* k2       = (const float*)d_in[6];
    const float* b2       = (const float*)d_in[7];
    float* out = (float*)d_out;

    char* ws = (char*)d_ws;
    int* sidx      = (int*)ws;                    // P_ROWS ints
    int* tile_base = sidx + P_ROWS;
    int* tile_task = tile_base + 512;
    int* tile_end  = tile_task + 512;
    int* ntiles    = tile_end + 512;

    size_t off = 131072;
    ushort_t* Wt0 = (ushort_t*)(ws + off); off += (size_t)16 * 512 * 1024 * 2;
    ushort_t* Wt1 = (ushort_t*)(ws + off); off += (size_t)16 * 1024 * 1024 * 2;
    ushort_t* Wt2 = (ushort_t*)(ws + off); off += (size_t)16 * 1024 * 256 * 2;

    bucket_kernel<<<1, 256, 0, stream>>>(task_ids, sidx, tile_base, tile_task,
                                         tile_end, ntiles);
    wconv< 512, 1024, 128><<<dim3(16,  8, 16), 256, 0, stream>>>(k0, Wt0);
    wconv<1024, 1024, 128><<<dim3(16, 16, 16), 256, 0, stream>>>(k1, Wt1);
    wconv<1024,  256,  32><<<dim3( 4, 16, 16), 256, 0, stream>>>(k2, Wt2);

    fused_mlp<<<NB_FUSED, 512, 0, stream>>>(
        x, Wt0, Wt1, Wt2, b0, b1, b2, out,
        sidx, tile_base, tile_task, tile_end, ntiles);
}

// Round 10
// 109.069 us; speedup vs baseline: 1.0782x; 1.0782x over previous
//
#include <hip/hip_runtime.h>
#include <math.h>

#define NUM_TASKS 16
#define B_ROWS    8192
#define TROWS     48               // rows per fused tile (3 x 16)
#define NB_FUSED  186              // max tiles: floor(8192/48) + 16
#define P_ROWS    8960             // padded sorted-row space (tasks 48-aligned)

typedef __attribute__((ext_vector_type(4))) float f32x4;
typedef __attribute__((ext_vector_type(8))) short bf16x8;
typedef __attribute__((ext_vector_type(4))) short bf16x4;
typedef unsigned short ushort_t;

__device__ __forceinline__ short f2bf(float f) {
    union { float f; unsigned u; } c; c.f = f;
    unsigned u = c.u;
    unsigned r = (u + 0x7FFFu + ((u >> 16) & 1u)) >> 16;
    return (short)r;
}

__device__ __forceinline__ float fast_tanh(float x) {
    float e = __expf(2.0f * x);
    return 1.0f - 2.0f / (e + 1.0f);
}

// ---------------------------------------------------------------------------
// W layout (per task, chunk-major wave granules; 256 cols per chunk,
// 32 cols per wave, 2 frags of 16 cols):
//  elem(n,k;K) = (((n>>8)*(K/32) + (k>>5))*8 + ((n>>5)&7))*1024
//              + ((n>>4)&1)*512 + ((k>>3)&3)*128 + (n&15)*8 + (k&7)
// One wave's 2 frags for one k32-step = 2 KB contiguous; step stride 16 KB
// (uniform across chunk boundaries -> continuous 4-deep register pipeline).
// H (LDS): 16-row groups, XOR slot swizzle ((m&15)^(kg&7)) — conflict-free.
// ---------------------------------------------------------------------------

// ---------------------------------------------------------------------------
// Bucket kernel: stable counting sort of rows by task, tasks padded to 48.
// ---------------------------------------------------------------------------
__global__ __launch_bounds__(256) void bucket_kernel(
    const int* __restrict__ task_ids,
    int* __restrict__ sidx,
    int* __restrict__ tile_base,
    int* __restrict__ tile_task,
    int* __restrict__ tile_end,
    int* __restrict__ ntiles)
{
    __shared__ int cnt[256][NUM_TASKS];
    __shared__ int pstart[NUM_TASKS];
    __shared__ int tot[NUM_TASKS];

    const int tid = threadIdx.x;
    #pragma unroll
    for (int t = 0; t < NUM_TASKS; ++t) cnt[tid][t] = 0;
    const int base = tid * (B_ROWS / 256);

    for (int i = 0; i < B_ROWS / 256; ++i) {
        int t = task_ids[base + i];
        cnt[tid][t]++;
    }
    __syncthreads();

    if (tid < NUM_TASKS) {
        int s = 0;
        for (int c = 0; c < 256; ++c) { int v = cnt[c][tid]; cnt[c][tid] = s; s += v; }
        tot[tid] = s;
    }
    __syncthreads();

    if (tid == 0) {
        int p = 0, nt = 0;
        for (int t = 0; t < NUM_TASKS; ++t) {
            pstart[t] = p;
            for (int r = 0; r < tot[t]; r += TROWS) {
                tile_base[nt] = p + r;
                tile_task[nt] = t;
                tile_end[nt]  = p + tot[t];
                nt++;
            }
            p += ((tot[t] + TROWS - 1) / TROWS) * TROWS;
        }
        *ntiles = nt;
    }
    __syncthreads();

    for (int i = 0; i < P_ROWS / 256; ++i) sidx[tid + i * 256] = 0;
    __syncthreads();

    for (int i = 0; i < B_ROWS / 256; ++i) {
        int row = base + i;
        int t = task_ids[row];
        int pos = pstart[t] + cnt[tid][t];
        cnt[tid][t] = cnt[tid][t] + 1;
        sidx[pos] = row;
    }
}

// ---------------------------------------------------------------------------
// Weight convert + transpose + pack into chunk-major granule layout.
// ---------------------------------------------------------------------------
template<int K, int N>
__global__ __launch_bounds__(256) void wconv(
    const float* __restrict__ W, ushort_t* __restrict__ Wt)
{
    const int t  = blockIdx.z;
    const int kb = blockIdx.y * 64;
    const int nb = blockIdx.x * 64;
    const float* src = W + (size_t)t * K * N;
    ushort_t* dst = Wt + (size_t)t * N * K;

    __shared__ ushort_t tile[64][68];

    const int tid = threadIdx.x;
    {
        int kl  = tid >> 4;
        int nl4 = (tid & 15) * 4;
        #pragma unroll
        for (int r = 0; r < 4; ++r) {
            int k = kl + r * 16;
            f32x4 v = *(const f32x4*)(src + (size_t)(kb + k) * N + nb + nl4);
            tile[nl4 + 0][k] = (ushort_t)f2bf(v[0]);
            tile[nl4 + 1][k] = (ushort_t)f2bf(v[1]);
            tile[nl4 + 2][k] = (ushort_t)f2bf(v[2]);
            tile[nl4 + 3][k] = (ushort_t)f2bf(v[3]);
        }
    }
    __syncthreads();
    {
        int nl = tid >> 2;            // 0..63 local n
        int c  = (tid & 3) * 16;      // local k chunk of 16
        int n  = nb + nl;
        int k0 = kb + c;
        bf16x4 v0 = *(const bf16x4*)&tile[nl][c + 0];
        bf16x4 v1 = *(const bf16x4*)&tile[nl][c + 4];
        bf16x4 v2 = *(const bf16x4*)&tile[nl][c + 8];
        bf16x4 v3 = *(const bf16x4*)&tile[nl][c + 12];
        ushort_t* dg = dst
            + (((size_t)(n >> 8) * (K / 32) + (k0 >> 5)) * 8 + ((n >> 5) & 7)) * 1024
            + ((n >> 4) & 1) * 512
            + ((k0 >> 3) & 3) * 128 + (n & 15) * 8;
        *(bf16x4*)(dg + 0)   = v0;
        *(bf16x4*)(dg + 4)   = v1;
        *(bf16x4*)(dg + 128) = v2;
        *(bf16x4*)(dg + 132) = v3;
    }
}

// ---------------------------------------------------------------------------
// One fused-MLP layer. Narrow W slice: 2 frags/wave/step (wreg[4][2] = 32
// VGPR), 4-deep register pipeline, continuous across the NC n-chunk loop
// (uniform 16 KB step stride). acc[NC][3][2] (96 regs, AGPR-resident MFMA
// C/D) held to layer end -> single write phase (in-place safe for layer 1).
// No barriers inside K/chunk loops.
// ---------------------------------------------------------------------------
template<int K, int NNOUT, int NC, int INPLACE, int FINAL>
__device__ __forceinline__ void run_layer(
    const char* __restrict__ Hin,
    char* __restrict__ Hout,
    const ushort_t* __restrict__ Wt,      // task's packed weights
    const float* __restrict__ bias,       // task's bias
    float* __restrict__ outp,
    const int* __restrict__ sidx,
    int rowbase, int rowend, int lane, int wid)
{
    constexpr int NS = K / 32;             // 16 or 32, %4==0

    const char* pw = (const char*)Wt
                   + wid * 2048 + (lane >> 4) * 256 + (lane & 15) * 16;

    f32x4 acc[NC][3][2];
    #pragma unroll
    for (int c = 0; c < NC; ++c)
        #pragma unroll
        for (int mf = 0; mf < 3; ++mf)
            #pragma unroll
            for (int nf = 0; nf < 2; ++nf)
                acc[c][mf][nf] = (f32x4){0.f, 0.f, 0.f, 0.f};

    bf16x8 wreg[4][2];
    #pragma unroll
    for (int b = 0; b < 4; ++b) {
        wreg[b][0] = *(const bf16x8*)(pw);
        wreg[b][1] = *(const bf16x8*)(pw + 1024);
        pw += 16384;
    }

    #pragma unroll
    for (int c = 0; c < NC; ++c) {
        #pragma unroll 4
        for (int s = 0; s < NS; ++s) {     // slot s&3 static per unrolled pos
            bf16x8 h[3];
            const int kg = s * 4 + (lane >> 4);
            #pragma unroll
            for (int mf = 0; mf < 3; ++mf)
                h[mf] = *(const bf16x8*)(Hin
                            + ((size_t)(mf * (K / 8) + kg) * 256)
                            + (((lane & 15) ^ (kg & 7)) * 16));
            __builtin_amdgcn_s_setprio(1);
            #pragma unroll
            for (int mf = 0; mf < 3; ++mf)
                #pragma unroll
                for (int nf = 0; nf < 2; ++nf)
                    acc[c][mf][nf] = __builtin_amdgcn_mfma_f32_16x16x32_bf16(
                        wreg[s & 3][nf], h[mf], acc[c][mf][nf], 0, 0, 0);
            __builtin_amdgcn_s_setprio(0);
            // reissue slot for granule (c*NS+s)+4; pad at buffer end covers
            // the tail over-issue (dead loads, never consumed).
            wreg[s & 3][0] = *(const bf16x8*)(pw);
            wreg[s & 3][1] = *(const bf16x8*)(pw + 1024);
            pw += 16384;
        }
    }

    const int q   = lane >> 4;
    const int m15 = lane & 15;

    if (!FINAL) {
        if (INPLACE) __syncthreads();      // all waves done reading H_in
        #pragma unroll
        for (int c = 0; c < NC; ++c) {
            #pragma unroll
            for (int mf = 0; mf < 3; ++mf) {
                #pragma unroll
                for (int nf = 0; nf < 2; ++nf) {
                    const int n_lo = c * 256 + wid * 32 + nf * 16 + q * 4;
                    const f32x4 bb = *(const f32x4*)(bias + n_lo);
                    bf16x4 pk;
                    #pragma unroll
                    for (int r = 0; r < 4; ++r)
                        pk[r] = f2bf(fast_tanh(acc[c][mf][nf][r] + bb[r]));
                    const int kg2 = n_lo >> 3;
                    size_t off = ((size_t)(mf * (NNOUT / 8) + kg2) * 256)
                               + ((m15 ^ (kg2 & 7)) * 16) + (n_lo & 7) * 2;
                    *(bf16x4*)(Hout + off) = pk;
                }
            }
        }
        __syncthreads();                   // H_out complete
    } else {
        #pragma unroll
        for (int mf = 0; mf < 3; ++mf) {
            const int grow = rowbase + mf * 16 + m15;
            if (grow < rowend) {
                const int orow = sidx[grow];
                #pragma unroll
                for (int nf = 0; nf < 2; ++nf) {
                    const int n_lo = wid * 32 + nf * 16 + q * 4;
                    const f32x4 bb = *(const f32x4*)(bias + n_lo);
                    f32x4 v;
                    #pragma unroll
                    for (int r = 0; r < 4; ++r)
                        v[r] = acc[0][mf][nf][r] + bb[r];
                    *(f32x4*)(outp + (size_t)orow * 256 + n_lo) = v;
                }
            }
        }
    }
}

// ---------------------------------------------------------------------------
// Fused 3-layer MLP: one 512-thread block per 48-row tile.
// LDS 144 KB: H region 96 KB + x region 48 KB.
// ---------------------------------------------------------------------------
__global__ __launch_bounds__(512, 2) void fused_mlp(
    const float* __restrict__ x,
    const ushort_t* __restrict__ Wt0,
    const ushort_t* __restrict__ Wt1,
    const ushort_t* __restrict__ Wt2,
    const float* __restrict__ b0,
    const float* __restrict__ b1,
    const float* __restrict__ b2,
    float* __restrict__ out,
    const int* __restrict__ sidx,
    const int* __restrict__ tile_base,
    const int* __restrict__ tile_task,
    const int* __restrict__ tile_end,
    const int* __restrict__ ntiles)
{
    __shared__ __align__(16) char lds[147456];
    char* Hreg = lds;            // 96 KB
    char* Xreg = lds + 98304;    // 48 KB

    // bijective XCD mapping (m204): contiguous ~23-tile (~2-task) chunk/XCD
    const int orig = blockIdx.x;
    constexpr int q8 = NB_FUSED / 8, r8 = NB_FUSED % 8;
    const int xcd = orig & 7, idx = orig >> 3;
    const int tile = (xcd < r8 ? xcd * (q8 + 1) : r8 * (q8 + 1) + (xcd - r8) * q8) + idx;

    if (tile >= *ntiles) return;
    const int rowbase = tile_base[tile];
    const int task    = tile_task[tile];
    const int rowend  = tile_end[tile];

    const int tid  = threadIdx.x;
    const int lane = tid & 63;
    const int wid  = tid >> 6;

    // ---- gather + convert x tile (48 rows x 512 fp32) into packed LDS ----
    #pragma unroll
    for (int i = 0; i < 6; ++i) {
        const int row = wid + i * 8;
        const int src = sidx[rowbase + row];
        const float* sp = x + (size_t)src * 512 + lane * 8;
        f32x4 v0 = *(const f32x4*)sp;
        f32x4 v1 = *(const f32x4*)(sp + 4);
        bf16x8 pk;
        pk[0] = f2bf(v0[0]); pk[1] = f2bf(v0[1]);
        pk[2] = f2bf(v0[2]); pk[3] = f2bf(v0[3]);
        pk[4] = f2bf(v1[0]); pk[5] = f2bf(v1[1]);
        pk[6] = f2bf(v1[2]); pk[7] = f2bf(v1[3]);
        size_t off = ((size_t)((row >> 4) * 64 + lane) * 256)
                   + (((row & 15) ^ (lane & 7)) * 16);
        *(bf16x8*)(Xreg + off) = pk;
    }
    __syncthreads();

    run_layer< 512, 1024, 4, 0, 0>(Xreg, Hreg,
                                   Wt0 + (size_t)task * 512 * 1024,
                                   b0 + task * 1024, nullptr, sidx,
                                   rowbase, rowend, lane, wid);
    run_layer<1024, 1024, 4, 1, 0>(Hreg, Hreg,
                                   Wt1 + (size_t)task * 1024 * 1024,
                                   b1 + task * 1024, nullptr, sidx,
                                   rowbase, rowend, lane, wid);
    run_layer<1024,  256, 1, 0, 1>(Hreg, nullptr,
                                   Wt2 + (size_t)task * 1024 * 256,
                                   b2 + task * 256, out, sidx,
                                   rowbase, rowend, lane, wid);
}

// ---------------------------------------------------------------------------
extern "C" void kernel_launch(void* const* d_in, const int* in_sizes, int n_in,
                              void* d_out, int out_size, void* d_ws, size_t ws_size,
                              hipStream_t stream)
{
    const float* x        = (const float*)d_in[0];
    const int*   task_ids = (const int*)  d_in[1];
    const float* k0       = (const float*)d_in[2];
    const float* b0       = (const float*)d_in[3];
    const float* k1       = (const float*)d_in[4];
    const float* b1       = (const float*)d_in[5];
    const float* k2       = (const float*)d_in[6];
    const float* b2       = (const float*)d_in[7];
    float* out = (float*)d_out;

    char* ws = (char*)d_ws;
    int* sidx      = (int*)ws;                    // P_ROWS ints
    int* tile_base = sidx + P_ROWS;
    int* tile_task = tile_base + 512;
    int* tile_end  = tile_task + 512;
    int* ntiles    = tile_end + 512;

    size_t off = 131072;
    // +65536 B pad per W buffer: pipeline tail over-issues up to 4 granules
    ushort_t* Wt0 = (ushort_t*)(ws + off); off += (size_t)16 * 512 * 1024 * 2 + 65536;
    ushort_t* Wt1 = (ushort_t*)(ws + off); off += (size_t)16 * 1024 * 1024 * 2 + 65536;
    ushort_t* Wt2 = (ushort_t*)(ws + off); off += (size_t)16 * 1024 * 256 * 2 + 65536;

    bucket_kernel<<<1, 256, 0, stream>>>(task_ids, sidx, tile_base, tile_task,
                                         tile_end, ntiles);
    wconv< 512, 1024><<<dim3(16,  8, 16), 256, 0, stream>>>(k0, Wt0);
    wconv<1024, 1024><<<dim3(16, 16, 16), 256, 0, stream>>>(k1, Wt1);
    wconv<1024,  256><<<dim3( 4, 16, 16), 256, 0, stream>>>(k2, Wt2);

    fused_mlp<<<NB_FUSED, 512, 0, stream>>>(
        x, Wt0, Wt1, Wt2, b0, b1, b2, out,
        sidx, tile_base, tile_task, tile_end, ntiles);
}